// Round 4
// baseline (284.746 us; speedup 1.0000x reference)
//
#include <hip/hip_runtime.h>
#include <stdint.h>

#define THREADS 256
#define DIM     10

typedef float v4f __attribute__((ext_vector_type(4)));

// Codebook is a (10,5) linear code: for k = b4 b3 b2 b1 b0 (MSB first),
// sign map s = 2b-1, the codeword is
//   [s4, s3, s2, s1, s0, -s0*s4, -s3*s4, -s2*s3, -s1*s2, -s0*s1]
// (verified element-wise against the reference table). argmax softmax(-d) ==
// argmax correlation (all ||c||^2 == 10, softmax/sqrt monotone), so we compute
// all 32 correlations with a shared-subexpression DP (~60 adds), fold the b4
// max via |S|, and rebuild the winner from its index bits. No tables, no LDS.

__device__ __forceinline__ void decide10(const float* __restrict__ x,
                                         float* __restrict__ y)
{
    const float x0=x[0], x1=x[1], x2=x[2], x3=x[3], x4=x[4];
    const float x5=x[5], x6=x[6], x7=x[7], x8=x[8], x9=x[9];

    // dot_k = R(b3,b2,b1,b0) + s4 * S(b3,b0)
    //   R = s3*G[b2] + s2*J[b1] + s1*L[b0] + s0*x4
    //   G = x1 - s2*x7, J = x2 - s1*x8, L = x3 - s0*x9, S = x0 - s0*x5 - s3*x6
    const float GP = x1 - x7, GM = x1 + x7;
    const float JP = x2 - x8, JM = x2 + x8;
    const float LP = x3 - x9, LM = x3 + x9;

    const float K11 =  LP + x4;
    const float K10 =  LM - x4;
    const float K01 =  x4 - LP;
    const float K00 = -LM - x4;

    const float H111 = JP + K11, H110 = JP + K10, H101 = JM + K01, H100 = JM + K00;
    const float H011 = K11 - JP, H010 = K10 - JP, H001 = K01 - JM, H000 = K00 - JM;

    float r[16];
    r[15] = GP + H111; r[14] = GP + H110; r[13] = GP + H101; r[12] = GP + H100;
    r[11] = GM + H011; r[10] = GM + H010; r[ 9] = GM + H001; r[ 8] = GM + H000;
    r[ 7] = H111 - GP; r[ 6] = H110 - GP; r[ 5] = H101 - GP; r[ 4] = H100 - GP;
    r[ 3] = H011 - GM; r[ 2] = H010 - GM; r[ 1] = H001 - GM; r[ 0] = H000 - GM;

    // S[b3][b0] = x0 - s0*x5 - s3*x6
    const float p56 = x5 + x6, m56 = x5 - x6;
    const float S11 = x0 - p56;
    const float S10 = x0 + m56;
    const float S01 = x0 - m56;
    const float S00 = x0 + p56;
    const float A11 = fabsf(S11), A10 = fabsf(S10), A01 = fabsf(S01), A00 = fabsf(S00);

    // m[i] = r[i] + |S|; b4-max folded (S==0 -> b4=0, lower k; argmax tie rule)
    float m[16];
    #pragma unroll
    for (int i = 0; i < 16; ++i) {
        const bool b3 = (i >> 3) & 1, b0 = i & 1;
        const float A = b3 ? (b0 ? A11 : A10) : (b0 ? A01 : A00);
        m[i] = r[i] + A;
    }

    float best = m[0];
    int   bi   = 0;
    #pragma unroll
    for (int i = 1; i < 16; ++i) {
        const bool c = m[i] > best;
        best = c ? m[i] : best;
        bi   = c ? i    : bi;
    }

    const int wb3 = (bi >> 3) & 1, wb0 = bi & 1;
    const float Sw = wb3 ? (wb0 ? S11 : S10) : (wb0 ? S01 : S00);
    const float s4 = (Sw > 0.0f) ? 1.0f : -1.0f;
    const float s0 = (bi & 1) ? 1.0f : -1.0f;
    const float s1 = (bi & 2) ? 1.0f : -1.0f;
    const float s2 = (bi & 4) ? 1.0f : -1.0f;
    const float s3 = (bi & 8) ? 1.0f : -1.0f;

    y[0] = s4;  y[1] = s3;  y[2] = s2;  y[3] = s1;  y[4] = s0;
    y[5] = -s0 * s4;  y[6] = -s3 * s4;  y[7] = -s2 * s3;
    y[8] = -s1 * s2;  y[9] = -s0 * s1;
}

// 2 points per thread: 20 floats = exactly 5 x dwordx4 in, 5 x dwordx4 out.
// Lane stride is 80 B; each 64 B line is fully consumed by nearby lanes within
// the wave's 5 consecutive accesses (L1-resident) -> full HBM line utilization
// with zero LDS, zero barriers, zero div-by-10 address math.
__global__ __launch_bounds__(THREADS) void softdec_kernel(
    const float* __restrict__ sig, float* __restrict__ out)
{
    const size_t t = (size_t)blockIdx.x * THREADS + threadIdx.x;
    const v4f* __restrict__ gin  = (const v4f*)sig + t * 5;
    v4f*       __restrict__ gout = (v4f*)out       + t * 5;

    const v4f a0 = gin[0], a1 = gin[1], a2 = gin[2], a3 = gin[3], a4 = gin[4];

    float x[20];
    x[ 0]=a0[0]; x[ 1]=a0[1]; x[ 2]=a0[2]; x[ 3]=a0[3];
    x[ 4]=a1[0]; x[ 5]=a1[1]; x[ 6]=a1[2]; x[ 7]=a1[3];
    x[ 8]=a2[0]; x[ 9]=a2[1]; x[10]=a2[2]; x[11]=a2[3];
    x[12]=a3[0]; x[13]=a3[1]; x[14]=a3[2]; x[15]=a3[3];
    x[16]=a4[0]; x[17]=a4[1]; x[18]=a4[2]; x[19]=a4[3];

    float y[20];
    decide10(x,      y);
    decide10(x + 10, y + 10);

    v4f o0, o1, o2, o3, o4;
    o0[0]=y[ 0]; o0[1]=y[ 1]; o0[2]=y[ 2]; o0[3]=y[ 3];
    o1[0]=y[ 4]; o1[1]=y[ 5]; o1[2]=y[ 6]; o1[3]=y[ 7];
    o2[0]=y[ 8]; o2[1]=y[ 9]; o2[2]=y[10]; o2[3]=y[11];
    o3[0]=y[12]; o3[1]=y[13]; o3[2]=y[14]; o3[3]=y[15];
    o4[0]=y[16]; o4[1]=y[17]; o4[2]=y[18]; o4[3]=y[19];

    gout[0] = o0; gout[1] = o1; gout[2] = o2; gout[3] = o3; gout[4] = o4;
}

extern "C" void kernel_launch(void* const* d_in, const int* in_sizes, int n_in,
                              void* d_out, int out_size, void* d_ws, size_t ws_size,
                              hipStream_t stream) {
    const float* sig = (const float*)d_in[0];
    float* out = (float*)d_out;
    const int total   = in_sizes[0];          // B*N*D = 41,943,040
    const int pts     = total / DIM;          // 4,194,304
    const int threads = pts / 2;              // 2,097,152 (2 pts/thread)
    const int blocks  = threads / THREADS;    // 8192 (exact)
    softdec_kernel<<<blocks, THREADS, 0, stream>>>(sig, out);
}

// Round 5
// 281.689 us; speedup vs baseline: 1.0109x; 1.0109x over previous
//
#include <hip/hip_runtime.h>
#include <stdint.h>

#define THREADS 256
#define DIM     10
// block = 512 points (2/thread) = 20480 B = 1280 v4f

typedef float v4f __attribute__((ext_vector_type(4)));

// Direct global->LDS DMA (16 B/lane). LDS dest is wave-uniform base + lane*16,
// which matches our linear staging layout exactly (guide §5, m97/m104).
__device__ __forceinline__ void gl_lds16(const v4f* g, v4f* l) {
    __builtin_amdgcn_global_load_lds(
        (const __attribute__((address_space(1))) void*)g,
        (__attribute__((address_space(3)))       void*)l,
        16, 0, 0);
}

// Codebook is a (10,5) linear code: for k = b4 b3 b2 b1 b0 (MSB first),
// sign map s = 2b-1, codeword = [s4,s3,s2,s1,s0, -s0s4,-s3s4,-s2s3,-s1s2,-s0s1]
// (verified element-wise vs the reference table). argmax softmax(-d) ==
// argmax correlation (||c||^2 == 10 for all k; sqrt/softmax monotone).
// All 32 correlations via shared-subexpression DP (~60 adds); b4-max folded
// through |S|; winner rebuilt from index bits. No tables, no gathers.
__device__ __forceinline__ void decide10(const float* __restrict__ x,
                                         float* __restrict__ y)
{
    const float x0=x[0], x1=x[1], x2=x[2], x3=x[3], x4=x[4];
    const float x5=x[5], x6=x[6], x7=x[7], x8=x[8], x9=x[9];

    const float GP = x1 - x7, GM = x1 + x7;
    const float JP = x2 - x8, JM = x2 + x8;
    const float LP = x3 - x9, LM = x3 + x9;

    const float K11 =  LP + x4;
    const float K10 =  LM - x4;
    const float K01 =  x4 - LP;
    const float K00 = -LM - x4;

    const float H111 = JP + K11, H110 = JP + K10, H101 = JM + K01, H100 = JM + K00;
    const float H011 = K11 - JP, H010 = K10 - JP, H001 = K01 - JM, H000 = K00 - JM;

    float r[16];
    r[15] = GP + H111; r[14] = GP + H110; r[13] = GP + H101; r[12] = GP + H100;
    r[11] = GM + H011; r[10] = GM + H010; r[ 9] = GM + H001; r[ 8] = GM + H000;
    r[ 7] = H111 - GP; r[ 6] = H110 - GP; r[ 5] = H101 - GP; r[ 4] = H100 - GP;
    r[ 3] = H011 - GM; r[ 2] = H010 - GM; r[ 1] = H001 - GM; r[ 0] = H000 - GM;

    const float p56 = x5 + x6, m56 = x5 - x6;
    const float S11 = x0 - p56;
    const float S10 = x0 + m56;
    const float S01 = x0 - m56;
    const float S00 = x0 + p56;
    const float A11 = fabsf(S11), A10 = fabsf(S10), A01 = fabsf(S01), A00 = fabsf(S00);

    float m[16];
    #pragma unroll
    for (int i = 0; i < 16; ++i) {
        const bool b3 = (i >> 3) & 1, b0 = i & 1;
        const float A = b3 ? (b0 ? A11 : A10) : (b0 ? A01 : A00);
        m[i] = r[i] + A;
    }

    float best = m[0];
    int   bi   = 0;
    #pragma unroll
    for (int i = 1; i < 16; ++i) {
        const bool c = m[i] > best;
        best = c ? m[i] : best;
        bi   = c ? i    : bi;
    }

    const int wb3 = (bi >> 3) & 1, wb0 = bi & 1;
    const float Sw = wb3 ? (wb0 ? S11 : S10) : (wb0 ? S01 : S00);
    const float s4 = (Sw > 0.0f) ? 1.0f : -1.0f;
    const float s0 = (bi & 1) ? 1.0f : -1.0f;
    const float s1 = (bi & 2) ? 1.0f : -1.0f;
    const float s2 = (bi & 4) ? 1.0f : -1.0f;
    const float s3 = (bi & 8) ? 1.0f : -1.0f;

    y[0] = s4;  y[1] = s3;  y[2] = s2;  y[3] = s1;  y[4] = s0;
    y[5] = -s0 * s4;  y[6] = -s3 * s4;  y[7] = -s2 * s3;
    y[8] = -s1 * s2;  y[9] = -s0 * s1;
}

__global__ __launch_bounds__(THREADS) void softdec_kernel(
    const float* __restrict__ sig, float* __restrict__ out)
{
    __shared__ v4f sBuf[THREADS * 5];            // 20 KB, reused in+out
    const int tid = threadIdx.x;
    const size_t blk = (size_t)blockIdx.x * (THREADS * 5);   // v4f units
    const v4f* __restrict__ gin  = (const v4f*)sig + blk;
    v4f*       __restrict__ gout = (v4f*)out       + blk;

    // ---- stage in: async global->LDS, 16 B/lane, fully coalesced ----
    #pragma unroll
    for (int it = 0; it < 5; ++it) {
        const int i = it * THREADS + tid;
        gl_lds16(&gin[i], &sBuf[i]);
    }
    __syncthreads();   // drains vmcnt for global_load_lds (m97 semantics)

    // ---- each thread: own 80 B region (lane stride 20 banks -> 2-way, free) ----
    const v4f a0 = sBuf[tid*5+0], a1 = sBuf[tid*5+1], a2 = sBuf[tid*5+2],
              a3 = sBuf[tid*5+3], a4 = sBuf[tid*5+4];

    float x[20];
    x[ 0]=a0[0]; x[ 1]=a0[1]; x[ 2]=a0[2]; x[ 3]=a0[3];
    x[ 4]=a1[0]; x[ 5]=a1[1]; x[ 6]=a1[2]; x[ 7]=a1[3];
    x[ 8]=a2[0]; x[ 9]=a2[1]; x[10]=a2[2]; x[11]=a2[3];
    x[12]=a3[0]; x[13]=a3[1]; x[14]=a3[2]; x[15]=a3[3];
    x[16]=a4[0]; x[17]=a4[1]; x[18]=a4[2]; x[19]=a4[3];

    float y[20];
    decide10(x,      y);
    decide10(x + 10, y + 10);

    v4f o;
    o[0]=y[ 0]; o[1]=y[ 1]; o[2]=y[ 2]; o[3]=y[ 3]; sBuf[tid*5+0] = o;
    o[0]=y[ 4]; o[1]=y[ 5]; o[2]=y[ 6]; o[3]=y[ 7]; sBuf[tid*5+1] = o;
    o[0]=y[ 8]; o[1]=y[ 9]; o[2]=y[10]; o[3]=y[11]; sBuf[tid*5+2] = o;
    o[0]=y[12]; o[1]=y[13]; o[2]=y[14]; o[3]=y[15]; sBuf[tid*5+3] = o;
    o[0]=y[16]; o[1]=y[17]; o[2]=y[18]; o[3]=y[19]; sBuf[tid*5+4] = o;
    __syncthreads();

    // ---- stage out: coalesced b128 LDS reads -> dwordx4 global stores ----
    #pragma unroll
    for (int it = 0; it < 5; ++it) {
        const int i = it * THREADS + tid;
        gout[i] = sBuf[i];
    }
}

extern "C" void kernel_launch(void* const* d_in, const int* in_sizes, int n_in,
                              void* d_out, int out_size, void* d_ws, size_t ws_size,
                              hipStream_t stream) {
    const float* sig = (const float*)d_in[0];
    float* out = (float*)d_out;
    const int total  = in_sizes[0];           // B*N*D = 41,943,040
    const int pts    = total / DIM;           // 4,194,304
    const int blocks = pts / (2 * THREADS);   // 8192 (exact, 512 pts/block)
    softdec_kernel<<<blocks, THREADS, 0, stream>>>(sig, out);
}